// Round 1
// baseline (1540.772 us; speedup 1.0000x reference)
//
#include <hip/hip_runtime.h>
#include <stdint.h>
#include <stddef.h>

#define FEATDIM 128
#define HIDDIM  256
#define CDIM    64
#define NHOPS   10

typedef __attribute__((ext_vector_type(8))) short bf16x8;
typedef __attribute__((ext_vector_type(4))) float f32x4;
typedef unsigned short u16;

__device__ __forceinline__ u16 f2bf(float f) {
  uint32_t u = __builtin_bit_cast(uint32_t, f);
  u = (u + 0x7fffu + ((u >> 16) & 1u)) >> 16;
  return (u16)u;
}
__device__ __forceinline__ float bf2f(u16 h) {
  uint32_t u = ((uint32_t)h) << 16;
  return __builtin_bit_cast(float, u);
}

// ---------------- conversions ----------------
__global__ void k_cvt_x(const float* __restrict__ x, u16* __restrict__ xb, int total) {
  int i = (blockIdx.x * blockDim.x + threadIdx.x) * 8;
  if (i >= total) return;
  if (i + 8 <= total) {
    const float4* p = (const float4*)(x + i);
    float4 a = p[0], b = p[1];
    bf16x8 v;
    v[0] = (short)f2bf(a.x); v[1] = (short)f2bf(a.y);
    v[2] = (short)f2bf(a.z); v[3] = (short)f2bf(a.w);
    v[4] = (short)f2bf(b.x); v[5] = (short)f2bf(b.y);
    v[6] = (short)f2bf(b.z); v[7] = (short)f2bf(b.w);
    *(bf16x8*)(xb + i) = v;
  } else {
    for (int j = i; j < total; ++j) xb[j] = f2bf(x[j]);
  }
}

// w: f32 row-major [K][N]  ->  wt: bf16 [N][K] (transposed)
__global__ void k_cvt_wt(const float* __restrict__ w, u16* __restrict__ wt, int K, int N) {
  int e = blockIdx.x * blockDim.x + threadIdx.x;
  if (e >= K * N) return;
  int k = e / N, n = e - k * N;
  wt[(size_t)n * K + k] = f2bf(w[e]);
}

// ---------------- bf16 MFMA GEMM: out = act(A @ W + b [+ A]) ----------------
// A: bf16 [M][K]; WT: bf16 [N][K]; tile BM=128, BN=64, BK=32; 4 waves, wave w -> rows [w*32,w*32+32)
template<int K, int N, bool RESID, bool PRELU, bool OUTF32>
__global__ __launch_bounds__(256) void k_gemm(const u16* __restrict__ A, const u16* __restrict__ WT,
                                              const float* __restrict__ bias, const float* __restrict__ pa_ptr,
                                              u16* __restrict__ outb, float* __restrict__ outf, int M) {
  __shared__ alignas(16) u16 Alds[128 * 32];
  __shared__ alignas(16) u16 Blds[64 * 32];
  const int t = threadIdx.x;
  const int w = t >> 6, l = t & 63;
  const int lr = l & 15, lk = l >> 4;     // fragment row/col, k-segment
  const int m0 = blockIdx.x * 128;
  const int n0 = blockIdx.y * 64;

  f32x4 acc[2][4];
#pragma unroll
  for (int a = 0; a < 2; ++a)
#pragma unroll
    for (int b = 0; b < 4; ++b)
#pragma unroll
      for (int i = 0; i < 4; ++i) acc[a][b][i] = 0.f;

  for (int k0 = 0; k0 < K; k0 += 32) {
    // stage A tile (128x32): 2 x 16B per thread, XOR-swizzled k-segment
#pragma unroll
    for (int s = 0; s < 2; ++s) {
      int slot = t + s * 256;
      int row = slot >> 2;
      int ks  = slot & 3;
      int gm = m0 + row; if (gm >= M) gm = M - 1;
      bf16x8 v = *(const bf16x8*)(A + (size_t)gm * K + k0 + ks * 8);
      int wks = ks ^ ((row >> 1) & 3);
      *(bf16x8*)&Alds[row * 32 + wks * 8] = v;
    }
    // stage B tile (64x32 from WT rows): 1 x 16B per thread
    {
      int row = t >> 2;
      int ks  = t & 3;
      bf16x8 v = *(const bf16x8*)(WT + (size_t)(n0 + row) * K + k0 + ks * 8);
      int wks = ks ^ ((row >> 1) & 3);
      *(bf16x8*)&Blds[row * 32 + wks * 8] = v;
    }
    __syncthreads();

    bf16x8 fa[2], fb[4];
#pragma unroll
    for (int mr = 0; mr < 2; ++mr) {
      int row = w * 32 + mr * 16 + lr;
      int ks = lk ^ ((row >> 1) & 3);
      fa[mr] = *(const bf16x8*)&Alds[row * 32 + ks * 8];
    }
#pragma unroll
    for (int nt = 0; nt < 4; ++nt) {
      int row = nt * 16 + lr;
      int ks = lk ^ ((row >> 1) & 3);
      fb[nt] = *(const bf16x8*)&Blds[row * 32 + ks * 8];
    }
#pragma unroll
    for (int mr = 0; mr < 2; ++mr)
#pragma unroll
      for (int nt = 0; nt < 4; ++nt)
        acc[mr][nt] = __builtin_amdgcn_mfma_f32_16x16x32_bf16(fa[mr], fb[nt], acc[mr][nt], 0, 0, 0);
    __syncthreads();
  }

  const float pa = PRELU ? pa_ptr[0] : 0.f;
#pragma unroll
  for (int mr = 0; mr < 2; ++mr) {
#pragma unroll
    for (int nt = 0; nt < 4; ++nt) {
#pragma unroll
      for (int i = 0; i < 4; ++i) {
        int row = m0 + w * 32 + mr * 16 + lk * 4 + i;   // C/D: row=(l>>4)*4+i
        int col = n0 + nt * 16 + lr;                    //      col=l&15
        if (row < M) {
          float v = acc[mr][nt][i] + bias[col];
          if constexpr (RESID) v += bf2f(A[(size_t)row * K + col]);  // K==N for residual layers
          if constexpr (PRELU) v = (v >= 0.f) ? v : pa * v;
          if constexpr (OUTF32) outf[(size_t)row * N + col] = v;
          else                  outb[(size_t)row * N + col] = f2bf(v);
        }
      }
    }
  }
}

// ---------------- CSR build ----------------
__global__ void k_hist(const int* __restrict__ dst, int* __restrict__ cnt, int E) {
  int e = blockIdx.x * blockDim.x + threadIdx.x;
  if (e < E) atomicAdd(&cnt[dst[e]], 1);
}

__global__ void k_scan1(const int* __restrict__ cnt, int* __restrict__ scn, int* __restrict__ bsum, int n) {
  __shared__ int s[256];
  int i = blockIdx.x * 256 + threadIdx.x;
  int v = (i < n) ? cnt[i] : 0;
  s[threadIdx.x] = v;
  __syncthreads();
  for (int off = 1; off < 256; off <<= 1) {
    int tv = (threadIdx.x >= off) ? s[threadIdx.x - off] : 0;
    __syncthreads();
    s[threadIdx.x] += tv;
    __syncthreads();
  }
  if (i < n) scn[i] = s[threadIdx.x];
  if (threadIdx.x == 255) bsum[blockIdx.x] = s[255];
}

__global__ void k_scan2(int* __restrict__ bsum, int B) {
  __shared__ int s[512];
  int v = (threadIdx.x < B) ? bsum[threadIdx.x] : 0;
  s[threadIdx.x] = v;
  __syncthreads();
  for (int off = 1; off < 512; off <<= 1) {
    int tv = (threadIdx.x >= off) ? s[threadIdx.x - off] : 0;
    __syncthreads();
    s[threadIdx.x] += tv;
    __syncthreads();
  }
  if (threadIdx.x < B) bsum[threadIdx.x] = s[threadIdx.x];
}

__global__ void k_scan3(const int* __restrict__ scn, const int* __restrict__ bsum, int* __restrict__ row_ptr, int n) {
  int i = blockIdx.x * 256 + threadIdx.x;
  if (i < n) {
    int off = (blockIdx.x > 0) ? bsum[blockIdx.x - 1] : 0;
    row_ptr[i + 1] = scn[i] + off;
  }
  if (i == 0) row_ptr[0] = 0;
}

__global__ void k_scatter(const int* __restrict__ src, const int* __restrict__ dst, const float* __restrict__ nrm,
                          const int* __restrict__ row_ptr, int* __restrict__ fill,
                          int* __restrict__ srcS, float* __restrict__ wS, int E) {
  int e = blockIdx.x * blockDim.x + threadIdx.x;
  if (e >= E) return;
  int d = dst[e];
  int p = atomicAdd(&fill[d], 1);
  int pos = row_ptr[d] + p;
  srcS[pos] = src[e];
  wS[pos]   = nrm[e];
}

// ---------------- propagation (wave per node, lane = channel) ----------------
__device__ __forceinline__ float wave_sum(float d) {
#pragma unroll
  for (int off = 32; off > 0; off >>= 1) d += __shfl_xor(d, off);
  return d;
}

__global__ void k_init(const float* __restrict__ z, const float* __restrict__ pw, const float* __restrict__ pb,
                       float* __restrict__ oacc, int N) {
  int n = blockIdx.x * 4 + (threadIdx.x >> 6);
  int c = threadIdx.x & 63;
  if (n >= N) return;
  float v = z[(size_t)n * CDIM + c];
  float d = wave_sum(v * pw[c]);
  float sc = 1.f / (1.f + expf(-(d + pb[0])));
  oacc[(size_t)n * CDIM + c] = sc * v;
}

__global__ void k_hop(const float* __restrict__ hc, const int* __restrict__ row_ptr,
                      const int* __restrict__ srcS, const float* __restrict__ wS,
                      const float* __restrict__ pw, const float* __restrict__ pb,
                      float* __restrict__ hn, float* __restrict__ oacc, int N) {
  int n = blockIdx.x * 4 + (threadIdx.x >> 6);
  int c = threadIdx.x & 63;
  if (n >= N) return;
  int beg = row_ptr[n], end = row_ptr[n + 1];
  float a = 0.f;
  int i = beg;
  for (; i + 1 < end; i += 2) {
    int s0 = srcS[i], s1 = srcS[i + 1];
    float w0 = wS[i], w1 = wS[i + 1];
    a += w0 * hc[(size_t)s0 * CDIM + c];
    a += w1 * hc[(size_t)s1 * CDIM + c];
  }
  if (i < end) {
    a += wS[i] * hc[(size_t)srcS[i] * CDIM + c];
  }
  hn[(size_t)n * CDIM + c] = a;
  float d = wave_sum(a * pw[c]);
  float sc = 1.f / (1.f + expf(-(d + pb[0])));
  oacc[(size_t)n * CDIM + c] += sc * a;
}

__global__ void k_lsm(const float* __restrict__ oacc, float* __restrict__ out, int N) {
  int n = blockIdx.x * 4 + (threadIdx.x >> 6);
  int c = threadIdx.x & 63;
  if (n >= N) return;
  float v = oacc[(size_t)n * CDIM + c];
  float m = v;
#pragma unroll
  for (int off = 32; off > 0; off >>= 1) m = fmaxf(m, __shfl_xor(m, off));
  float e = expf(v - m);
  float s = wave_sum(e);
  out[(size_t)n * CDIM + c] = (v - m) - logf(s);
}

// ---------------- launch ----------------
extern "C" void kernel_launch(void* const* d_in, const int* in_sizes, int n_in,
                              void* d_out, int out_size, void* d_ws, size_t ws_size,
                              hipStream_t stream) {
  const float* x   = (const float*)d_in[0];
  const int*   ei  = (const int*)d_in[1];
  const float* nrm = (const float*)d_in[2];
  const float* W1  = (const float*)d_in[3];
  const float* b1  = (const float*)d_in[4];
  const float* W2  = (const float*)d_in[5];
  const float* b2  = (const float*)d_in[6];
  const float* W3  = (const float*)d_in[7];
  const float* b3  = (const float*)d_in[8];
  const float* W4  = (const float*)d_in[9];
  const float* b4  = (const float*)d_in[10];
  const float* pa  = (const float*)d_in[11];
  const float* pw  = (const float*)d_in[12];
  const float* pb  = (const float*)d_in[13];
  float* out = (float*)d_out;

  const int M = in_sizes[0] / FEATDIM;
  const int E = in_sizes[1] / 2;
  const int* srcI = ei;
  const int* dstI = ei + E;

  char* ws = (char*)d_ws;
  size_t o = 0;
  auto alloc = [&](size_t bytes) { size_t r = o; o += (bytes + 15) & ~(size_t)15; return r; };
  size_t oX  = alloc((size_t)M * 256);          // xb (bf16 M*128) then z (f32 M*64)
  size_t oA  = alloc((size_t)M * 512);          // hA: bf16 M*256
  size_t oB  = alloc((size_t)M * 512);          // hB: bf16 M*256; later P0,P1 (f32 M*64 each)
  size_t oO  = alloc((size_t)M * 256);          // oacc f32 M*64
  size_t oW1 = alloc((size_t)FEATDIM * HIDDIM * 2);
  size_t oW2 = alloc((size_t)HIDDIM * HIDDIM * 2);
  size_t oW3 = alloc((size_t)HIDDIM * HIDDIM * 2);
  size_t oW4 = alloc((size_t)HIDDIM * CDIM * 2);
  size_t oRP = alloc((size_t)(M + 1) * 4);      // row_ptr
  size_t oSC = alloc((size_t)M * 4);            // scn
  size_t oBS = alloc(4096);                     // block sums (<=512 blocks of 256)
  size_t oCN = alloc((size_t)M * 4);            // counts
  size_t oFI = alloc((size_t)M * 4);            // fill
  size_t oSS = alloc((size_t)E * 4);            // src sorted
  size_t oWW = alloc((size_t)E * 4);            // weight sorted

  u16*  xb   = (u16*)(ws + oX);
  float* z   = (float*)(ws + oX);
  u16*  hA   = (u16*)(ws + oA);
  u16*  hB   = (u16*)(ws + oB);
  float* P0  = (float*)(ws + oB);
  float* P1  = (float*)(ws + oB + (size_t)M * 256);
  float* oacc= (float*)(ws + oO);
  u16*  wt1  = (u16*)(ws + oW1);
  u16*  wt2  = (u16*)(ws + oW2);
  u16*  wt3  = (u16*)(ws + oW3);
  u16*  wt4  = (u16*)(ws + oW4);
  int*  rowp = (int*)(ws + oRP);
  int*  scn  = (int*)(ws + oSC);
  int*  bsum = (int*)(ws + oBS);
  int*  cnt  = (int*)(ws + oCN);
  int*  fill = (int*)(ws + oFI);
  int*  srcS = (int*)(ws + oSS);
  float* wS  = (float*)(ws + oWW);

  // conversions
  k_cvt_x<<<(M * FEATDIM / 8 + 255) / 256, 256, 0, stream>>>(x, xb, M * FEATDIM);
  k_cvt_wt<<<(FEATDIM * HIDDIM + 255) / 256, 256, 0, stream>>>(W1, wt1, FEATDIM, HIDDIM);
  k_cvt_wt<<<(HIDDIM * HIDDIM + 255) / 256, 256, 0, stream>>>(W2, wt2, HIDDIM, HIDDIM);
  k_cvt_wt<<<(HIDDIM * HIDDIM + 255) / 256, 256, 0, stream>>>(W3, wt3, HIDDIM, HIDDIM);
  k_cvt_wt<<<(HIDDIM * CDIM + 255) / 256, 256, 0, stream>>>(W4, wt4, HIDDIM, CDIM);

  // CSR build (sorted-by-dst edge list -> no atomics in the hop loop)
  hipMemsetAsync(ws + oCN, 0, (size_t)M * 4, stream);
  hipMemsetAsync(ws + oFI, 0, (size_t)M * 4, stream);
  k_hist<<<(E + 255) / 256, 256, 0, stream>>>(dstI, cnt, E);
  int nb = (M + 255) / 256;
  k_scan1<<<nb, 256, 0, stream>>>(cnt, scn, bsum, M);
  k_scan2<<<1, 512, 0, stream>>>(bsum, nb);
  k_scan3<<<nb, 256, 0, stream>>>(scn, bsum, rowp, M);
  k_scatter<<<(E + 255) / 256, 256, 0, stream>>>(srcI, dstI, nrm, rowp, fill, srcS, wS, E);

  // MLP
  dim3 blk(256);
  dim3 gH((M + 127) / 128, HIDDIM / 64);
  dim3 gC((M + 127) / 128, 1);
  k_gemm<FEATDIM, HIDDIM, false, true,  false><<<gH, blk, 0, stream>>>(xb, wt1, b1, pa, hA, nullptr, M);
  k_gemm<HIDDIM,  HIDDIM, true,  true,  false><<<gH, blk, 0, stream>>>(hA, wt2, b2, pa, hB, nullptr, M);
  k_gemm<HIDDIM,  HIDDIM, true,  true,  false><<<gH, blk, 0, stream>>>(hB, wt3, b3, pa, hA, nullptr, M);
  k_gemm<HIDDIM,  CDIM,   false, false, true ><<<gC, blk, 0, stream>>>(hA, wt4, b4, pa, nullptr, z, M);

  // propagation with fused adaptive-score accumulation
  int nblk = (M + 3) / 4;
  k_init<<<nblk, 256, 0, stream>>>(z, pw, pb, oacc, M);
  const float* cur = z;
  for (int k = 0; k < NHOPS; ++k) {
    float* dbuf = (k & 1) ? P1 : P0;
    k_hop<<<nblk, 256, 0, stream>>>(cur, rowp, srcS, wS, pw, pb, dbuf, oacc, M);
    cur = dbuf;
  }
  k_lsm<<<nblk, 256, 0, stream>>>(oacc, out, M);
}

// Round 2
// 1021.936 us; speedup vs baseline: 1.5077x; 1.5077x over previous
//
#include <hip/hip_runtime.h>
#include <stdint.h>
#include <stddef.h>

#define FEATDIM 128
#define HIDDIM  256
#define CDIM    64
#define NHOPS   10

typedef __attribute__((ext_vector_type(8))) short bf16x8;
typedef __attribute__((ext_vector_type(4))) float f32x4;
typedef unsigned short u16;

__device__ __forceinline__ u16 f2bf(float f) {
  uint32_t u = __builtin_bit_cast(uint32_t, f);
  u = (u + 0x7fffu + ((u >> 16) & 1u)) >> 16;
  return (u16)u;
}
__device__ __forceinline__ float bf2f(u16 h) {
  uint32_t u = ((uint32_t)h) << 16;
  return __builtin_bit_cast(float, u);
}

// ---------------- conversions ----------------
__global__ void k_cvt_x(const float* __restrict__ x, u16* __restrict__ xb, int total) {
  int i = (blockIdx.x * blockDim.x + threadIdx.x) * 8;
  if (i >= total) return;
  if (i + 8 <= total) {
    const float4* p = (const float4*)(x + i);
    float4 a = p[0], b = p[1];
    bf16x8 v;
    v[0] = (short)f2bf(a.x); v[1] = (short)f2bf(a.y);
    v[2] = (short)f2bf(a.z); v[3] = (short)f2bf(a.w);
    v[4] = (short)f2bf(b.x); v[5] = (short)f2bf(b.y);
    v[6] = (short)f2bf(b.z); v[7] = (short)f2bf(b.w);
    *(bf16x8*)(xb + i) = v;
  } else {
    for (int j = i; j < total; ++j) xb[j] = f2bf(x[j]);
  }
}

// w: f32 row-major [K][N]  ->  wt: bf16 [N][K] (transposed)
__global__ void k_cvt_wt(const float* __restrict__ w, u16* __restrict__ wt, int K, int N) {
  int e = blockIdx.x * blockDim.x + threadIdx.x;
  if (e >= K * N) return;
  int k = e / N, n = e - k * N;
  wt[(size_t)n * K + k] = f2bf(w[e]);
}

// ---------------- bf16 MFMA GEMM: out = act(A @ W + b [+ A]) ----------------
template<int K, int N, bool RESID, bool PRELU>
__global__ __launch_bounds__(256) void k_gemm(const u16* __restrict__ A, const u16* __restrict__ WT,
                                              const float* __restrict__ bias, const float* __restrict__ pa_ptr,
                                              u16* __restrict__ outb, int M) {
  __shared__ alignas(16) u16 Alds[128 * 32];
  __shared__ alignas(16) u16 Blds[64 * 32];
  const int t = threadIdx.x;
  const int w = t >> 6, l = t & 63;
  const int lr = l & 15, lk = l >> 4;
  const int m0 = blockIdx.x * 128;
  const int n0 = blockIdx.y * 64;

  f32x4 acc[2][4];
#pragma unroll
  for (int a = 0; a < 2; ++a)
#pragma unroll
    for (int b = 0; b < 4; ++b)
#pragma unroll
      for (int i = 0; i < 4; ++i) acc[a][b][i] = 0.f;

  for (int k0 = 0; k0 < K; k0 += 32) {
#pragma unroll
    for (int s = 0; s < 2; ++s) {
      int slot = t + s * 256;
      int row = slot >> 2;
      int ks  = slot & 3;
      int gm = m0 + row; if (gm >= M) gm = M - 1;
      bf16x8 v = *(const bf16x8*)(A + (size_t)gm * K + k0 + ks * 8);
      int wks = ks ^ ((row >> 1) & 3);
      *(bf16x8*)&Alds[row * 32 + wks * 8] = v;
    }
    {
      int row = t >> 2;
      int ks  = t & 3;
      bf16x8 v = *(const bf16x8*)(WT + (size_t)(n0 + row) * K + k0 + ks * 8);
      int wks = ks ^ ((row >> 1) & 3);
      *(bf16x8*)&Blds[row * 32 + wks * 8] = v;
    }
    __syncthreads();

    bf16x8 fa[2], fb[4];
#pragma unroll
    for (int mr = 0; mr < 2; ++mr) {
      int row = w * 32 + mr * 16 + lr;
      int ks = lk ^ ((row >> 1) & 3);
      fa[mr] = *(const bf16x8*)&Alds[row * 32 + ks * 8];
    }
#pragma unroll
    for (int nt = 0; nt < 4; ++nt) {
      int row = nt * 16 + lr;
      int ks = lk ^ ((row >> 1) & 3);
      fb[nt] = *(const bf16x8*)&Blds[row * 32 + ks * 8];
    }
#pragma unroll
    for (int mr = 0; mr < 2; ++mr)
#pragma unroll
      for (int nt = 0; nt < 4; ++nt)
        acc[mr][nt] = __builtin_amdgcn_mfma_f32_16x16x32_bf16(fa[mr], fb[nt], acc[mr][nt], 0, 0, 0);
    __syncthreads();
  }

  const float pa = PRELU ? pa_ptr[0] : 0.f;
#pragma unroll
  for (int mr = 0; mr < 2; ++mr) {
#pragma unroll
    for (int nt = 0; nt < 4; ++nt) {
#pragma unroll
      for (int i = 0; i < 4; ++i) {
        int row = m0 + w * 32 + mr * 16 + lk * 4 + i;
        int col = n0 + nt * 16 + lr;
        if (row < M) {
          float v = acc[mr][nt][i] + bias[col];
          if constexpr (RESID) v += bf2f(A[(size_t)row * K + col]);
          if constexpr (PRELU) v = (v >= 0.f) ? v : pa * v;
          outb[(size_t)row * N + col] = f2bf(v);
        }
      }
    }
  }
}

// ---------------- CSR build ----------------
// hist + per-edge rank in one pass (rank = stable position within dst bucket)
__global__ void k_hist(const int* __restrict__ dst, int* __restrict__ cnt, int* __restrict__ rank, int E) {
  int e = blockIdx.x * blockDim.x + threadIdx.x;
  if (e < E) rank[e] = atomicAdd(&cnt[dst[e]], 1);
}

__global__ void k_scan1(const int* __restrict__ cnt, int* __restrict__ scn, int* __restrict__ bsum, int n) {
  __shared__ int s[256];
  int i = blockIdx.x * 256 + threadIdx.x;
  int v = (i < n) ? cnt[i] : 0;
  s[threadIdx.x] = v;
  __syncthreads();
  for (int off = 1; off < 256; off <<= 1) {
    int tv = (threadIdx.x >= off) ? s[threadIdx.x - off] : 0;
    __syncthreads();
    s[threadIdx.x] += tv;
    __syncthreads();
  }
  if (i < n) scn[i] = s[threadIdx.x];
  if (threadIdx.x == 255) bsum[blockIdx.x] = s[255];
}

__global__ void k_scan2(int* __restrict__ bsum, int B) {
  __shared__ int s[512];
  int v = (threadIdx.x < B) ? bsum[threadIdx.x] : 0;
  s[threadIdx.x] = v;
  __syncthreads();
  for (int off = 1; off < 512; off <<= 1) {
    int tv = (threadIdx.x >= off) ? s[threadIdx.x - off] : 0;
    __syncthreads();
    s[threadIdx.x] += tv;
    __syncthreads();
  }
  if (threadIdx.x < B) bsum[threadIdx.x] = s[threadIdx.x];
}

__global__ void k_scan3(const int* __restrict__ scn, const int* __restrict__ bsum, int* __restrict__ row_ptr, int n) {
  int i = blockIdx.x * 256 + threadIdx.x;
  if (i < n) {
    int off = (blockIdx.x > 0) ? bsum[blockIdx.x - 1] : 0;
    row_ptr[i + 1] = scn[i] + off;
  }
  if (i == 0) row_ptr[0] = 0;
}

// single 8B store per edge: {src, bits(norm)}
__global__ void k_scatter(const int* __restrict__ src, const int* __restrict__ dst, const float* __restrict__ nrm,
                          const int* __restrict__ row_ptr, const int* __restrict__ rank,
                          int2* __restrict__ ed, int E) {
  int e = blockIdx.x * blockDim.x + threadIdx.x;
  if (e >= E) return;
  int d = dst[e];
  int pos = row_ptr[d] + rank[e];
  ed[pos] = make_int2(src[e], __builtin_bit_cast(int, nrm[e]));
}

// ---------------- propagation (wave per node, lane = channel, bf16 state) ----------------
__device__ __forceinline__ float wave_sum(float d) {
#pragma unroll
  for (int off = 32; off > 0; off >>= 1) d += __shfl_xor(d, off);
  return d;
}

__global__ void k_init(const u16* __restrict__ zb, const float* __restrict__ pw, const float* __restrict__ pb,
                       float* __restrict__ oacc, int N) {
  int n = blockIdx.x * 4 + (threadIdx.x >> 6);
  int c = threadIdx.x & 63;
  if (n >= N) return;
  float v = bf2f(zb[(size_t)n * CDIM + c]);
  float d = wave_sum(v * pw[c]);
  float sc = 1.f / (1.f + expf(-(d + pb[0])));
  oacc[(size_t)n * CDIM + c] = sc * v;
}

__global__ void k_hop(const u16* __restrict__ hc, const int* __restrict__ row_ptr,
                      const int2* __restrict__ ed,
                      const float* __restrict__ pw, const float* __restrict__ pb,
                      u16* __restrict__ hn, float* __restrict__ oacc, int N) {
  int n = blockIdx.x * 4 + (threadIdx.x >> 6);
  int c = threadIdx.x & 63;
  if (n >= N) return;
  int beg = row_ptr[n], end = row_ptr[n + 1];
  int deg = end - beg;

  // wave-cooperative edge prefetch: lane l holds edge beg+l
  int2 e0 = make_int2(0, 0);
  if (c < deg) e0 = ed[beg + c];

  float a = 0.f;
  int jn = (deg < 64) ? deg : 64;
  int j = 0;
  for (; j + 3 < jn; j += 4) {
    int s0 = __shfl(e0.x, j);     int s1 = __shfl(e0.x, j + 1);
    int s2 = __shfl(e0.x, j + 2); int s3 = __shfl(e0.x, j + 3);
    float w0 = __builtin_bit_cast(float, __shfl(e0.y, j));
    float w1 = __builtin_bit_cast(float, __shfl(e0.y, j + 1));
    float w2 = __builtin_bit_cast(float, __shfl(e0.y, j + 2));
    float w3 = __builtin_bit_cast(float, __shfl(e0.y, j + 3));
    float h0 = bf2f(hc[(size_t)s0 * CDIM + c]);
    float h1 = bf2f(hc[(size_t)s1 * CDIM + c]);
    float h2 = bf2f(hc[(size_t)s2 * CDIM + c]);
    float h3 = bf2f(hc[(size_t)s3 * CDIM + c]);
    a += w0 * h0; a += w1 * h1; a += w2 * h2; a += w3 * h3;
  }
  for (; j < jn; ++j) {
    int s = __shfl(e0.x, j);
    float w = __builtin_bit_cast(float, __shfl(e0.y, j));
    a += w * bf2f(hc[(size_t)s * CDIM + c]);
  }
  // rare overflow (deg > 64)
  for (int i = beg + 64; i < end; ++i) {
    int2 e = ed[i];
    a += __builtin_bit_cast(float, e.y) * bf2f(hc[(size_t)e.x * CDIM + c]);
  }

  hn[(size_t)n * CDIM + c] = f2bf(a);
  float d = wave_sum(a * pw[c]);
  float sc = 1.f / (1.f + expf(-(d + pb[0])));
  oacc[(size_t)n * CDIM + c] += sc * a;
}

__global__ void k_lsm(const float* __restrict__ oacc, float* __restrict__ out, int N) {
  int n = blockIdx.x * 4 + (threadIdx.x >> 6);
  int c = threadIdx.x & 63;
  if (n >= N) return;
  float v = oacc[(size_t)n * CDIM + c];
  float m = v;
#pragma unroll
  for (int off = 32; off > 0; off >>= 1) m = fmaxf(m, __shfl_xor(m, off));
  float e = expf(v - m);
  float s = wave_sum(e);
  out[(size_t)n * CDIM + c] = (v - m) - logf(s);
}

// ---------------- launch ----------------
extern "C" void kernel_launch(void* const* d_in, const int* in_sizes, int n_in,
                              void* d_out, int out_size, void* d_ws, size_t ws_size,
                              hipStream_t stream) {
  const float* x   = (const float*)d_in[0];
  const int*   ei  = (const int*)d_in[1];
  const float* nrm = (const float*)d_in[2];
  const float* W1  = (const float*)d_in[3];
  const float* b1  = (const float*)d_in[4];
  const float* W2  = (const float*)d_in[5];
  const float* b2  = (const float*)d_in[6];
  const float* W3  = (const float*)d_in[7];
  const float* b3  = (const float*)d_in[8];
  const float* W4  = (const float*)d_in[9];
  const float* b4  = (const float*)d_in[10];
  const float* pa  = (const float*)d_in[11];
  const float* pw  = (const float*)d_in[12];
  const float* pb  = (const float*)d_in[13];
  float* out = (float*)d_out;

  const int M = in_sizes[0] / FEATDIM;
  const int E = in_sizes[1] / 2;
  const int* srcI = ei;
  const int* dstI = ei + E;

  char* ws = (char*)d_ws;
  size_t o = 0;
  auto alloc = [&](size_t bytes) { size_t r = o; o += (bytes + 15) & ~(size_t)15; return r; };
  size_t oX  = alloc((size_t)M * 256);          // xb (bf16 M*128); later zb + P0 (bf16 M*64 each)
  size_t oA  = alloc((size_t)M * 512);          // hA bf16 M*256; rank (E*4) aliases here pre-MLP
  size_t oB  = alloc((size_t)M * 512);          // hB bf16 M*256; later P1
  size_t oO  = alloc((size_t)M * 256);          // oacc f32 M*64
  size_t oW1 = alloc((size_t)FEATDIM * HIDDIM * 2);
  size_t oW2 = alloc((size_t)HIDDIM * HIDDIM * 2);
  size_t oW3 = alloc((size_t)HIDDIM * HIDDIM * 2);
  size_t oW4 = alloc((size_t)HIDDIM * CDIM * 2);
  size_t oRP = alloc((size_t)(M + 1) * 4);      // row_ptr
  size_t oSC = alloc((size_t)M * 4);            // scn
  size_t oBS = alloc(4096);                     // block sums
  size_t oCN = alloc((size_t)M * 4);            // counts
  size_t oED = alloc((size_t)E * 8);            // edge struct {src, w}

  u16*  xb   = (u16*)(ws + oX);
  u16*  zb   = (u16*)(ws + oX);
  u16*  P0   = (u16*)(ws + oX + (size_t)M * 128);
  u16*  hA   = (u16*)(ws + oA);
  int*  rank = (int*)(ws + oA);                 // CSR-build phase only (pre-GEMM)
  u16*  hB   = (u16*)(ws + oB);
  u16*  P1   = (u16*)(ws + oB);
  float* oacc= (float*)(ws + oO);
  u16*  wt1  = (u16*)(ws + oW1);
  u16*  wt2  = (u16*)(ws + oW2);
  u16*  wt3  = (u16*)(ws + oW3);
  u16*  wt4  = (u16*)(ws + oW4);
  int*  rowp = (int*)(ws + oRP);
  int*  scn  = (int*)(ws + oSC);
  int*  bsum = (int*)(ws + oBS);
  int*  cnt  = (int*)(ws + oCN);
  int2* ed   = (int2*)(ws + oED);

  // conversions
  k_cvt_x<<<(M * FEATDIM / 8 + 255) / 256, 256, 0, stream>>>(x, xb, M * FEATDIM);
  k_cvt_wt<<<(FEATDIM * HIDDIM + 255) / 256, 256, 0, stream>>>(W1, wt1, FEATDIM, HIDDIM);
  k_cvt_wt<<<(HIDDIM * HIDDIM + 255) / 256, 256, 0, stream>>>(W2, wt2, HIDDIM, HIDDIM);
  k_cvt_wt<<<(HIDDIM * HIDDIM + 255) / 256, 256, 0, stream>>>(W3, wt3, HIDDIM, HIDDIM);
  k_cvt_wt<<<(HIDDIM * CDIM + 255) / 256, 256, 0, stream>>>(W4, wt4, HIDDIM, CDIM);

  // CSR build
  hipMemsetAsync(ws + oCN, 0, (size_t)M * 4, stream);
  k_hist<<<(E + 255) / 256, 256, 0, stream>>>(dstI, cnt, rank, E);
  int nb = (M + 255) / 256;
  k_scan1<<<nb, 256, 0, stream>>>(cnt, scn, bsum, M);
  k_scan2<<<1, 512, 0, stream>>>(bsum, nb);
  k_scan3<<<nb, 256, 0, stream>>>(scn, bsum, rowp, M);
  k_scatter<<<(E + 255) / 256, 256, 0, stream>>>(srcI, dstI, nrm, rowp, rank, ed, E);

  // MLP (rank region is dead from here on; hA may overwrite it)
  dim3 blk(256);
  dim3 gH((M + 127) / 128, HIDDIM / 64);
  dim3 gC((M + 127) / 128, 1);
  k_gemm<FEATDIM, HIDDIM, false, true ><<<gH, blk, 0, stream>>>(xb, wt1, b1, pa, hA, M);
  k_gemm<HIDDIM,  HIDDIM, true,  true ><<<gH, blk, 0, stream>>>(hA, wt2, b2, pa, hB, M);
  k_gemm<HIDDIM,  HIDDIM, true,  true ><<<gH, blk, 0, stream>>>(hB, wt3, b3, pa, hA, M);
  k_gemm<HIDDIM,  CDIM,   false, false><<<gC, blk, 0, stream>>>(hA, wt4, b4, pa, zb, M);

  // propagation with fused adaptive-score accumulation
  int nblk = (M + 3) / 4;
  k_init<<<nblk, 256, 0, stream>>>(zb, pw, pb, oacc, M);
  const u16* cur = zb;
  for (int k = 0; k < NHOPS; ++k) {
    u16* dbuf = (k & 1) ? P1 : P0;
    k_hop<<<nblk, 256, 0, stream>>>(cur, rowp, ed, pw, pb, dbuf, oacc, M);
    cur = dbuf;
  }
  k_lsm<<<nblk, 256, 0, stream>>>(oacc, out, M);
}

// Round 3
// 1002.247 us; speedup vs baseline: 1.5373x; 1.0196x over previous
//
#include <hip/hip_runtime.h>
#include <stdint.h>
#include <stddef.h>

#define FEATDIM 128
#define HIDDIM  256
#define CDIM    64
#define NHOPS   10

typedef __attribute__((ext_vector_type(8))) short bf16x8;
typedef __attribute__((ext_vector_type(4))) float f32x4;
typedef unsigned short u16;

__device__ __forceinline__ u16 f2bf(float f) {
  uint32_t u = __builtin_bit_cast(uint32_t, f);
  u = (u + 0x7fffu + ((u >> 16) & 1u)) >> 16;
  return (u16)u;
}
__device__ __forceinline__ float bf2f(u16 h) {
  uint32_t u = ((uint32_t)h) << 16;
  return __builtin_bit_cast(float, u);
}

// ---------------- conversions ----------------
__global__ void k_cvt_x(const float* __restrict__ x, u16* __restrict__ xb, int total) {
  int i = (blockIdx.x * blockDim.x + threadIdx.x) * 8;
  if (i >= total) return;
  if (i + 8 <= total) {
    const float4* p = (const float4*)(x + i);
    float4 a = p[0], b = p[1];
    bf16x8 v;
    v[0] = (short)f2bf(a.x); v[1] = (short)f2bf(a.y);
    v[2] = (short)f2bf(a.z); v[3] = (short)f2bf(a.w);
    v[4] = (short)f2bf(b.x); v[5] = (short)f2bf(b.y);
    v[6] = (short)f2bf(b.z); v[7] = (short)f2bf(b.w);
    *(bf16x8*)(xb + i) = v;
  } else {
    for (int j = i; j < total; ++j) xb[j] = f2bf(x[j]);
  }
}

__global__ void k_cvt_wt(const float* __restrict__ w, u16* __restrict__ wt, int K, int N) {
  int e = blockIdx.x * blockDim.x + threadIdx.x;
  if (e >= K * N) return;
  int k = e / N, n = e - k * N;
  wt[(size_t)n * K + k] = f2bf(w[e]);
}

// ---------------- bf16 MFMA GEMM, BN = 256 (full hidden), 8 waves ----------------
// A: bf16 [M][K]; WT: bf16 [256][K]; out: bf16 [M][256]; PReLU always on.
template<int K, bool RESID>
__global__ __launch_bounds__(512) void k_gemm_bn(const u16* __restrict__ A, const u16* __restrict__ WT,
                                                 const float* __restrict__ bias, const float* __restrict__ pa_ptr,
                                                 u16* __restrict__ outb, int M) {
  __shared__ alignas(16) u16 Alds[128 * 32];
  __shared__ alignas(16) u16 Blds[256 * 32];
  const int t = threadIdx.x;
  const int w = t >> 6, l = t & 63;
  const int wr = w >> 2, wc = w & 3;        // 2x4 wave grid: 64x64 per wave
  const int lr = l & 15, lk = l >> 4;
  const int m0 = blockIdx.x * 128;

  f32x4 acc[4][4];
#pragma unroll
  for (int a = 0; a < 4; ++a)
#pragma unroll
    for (int b = 0; b < 4; ++b)
#pragma unroll
      for (int i = 0; i < 4; ++i) acc[a][b][i] = 0.f;

  for (int k0 = 0; k0 < K; k0 += 32) {
    {  // A tile 128x32: 512 slots, 1 per thread
      int row = t >> 2, ks = t & 3;
      int gm = m0 + row; if (gm >= M) gm = M - 1;
      bf16x8 v = *(const bf16x8*)(A + (size_t)gm * K + k0 + ks * 8);
      int wks = ks ^ ((row >> 1) & 3);
      *(bf16x8*)&Alds[row * 32 + wks * 8] = v;
    }
#pragma unroll
    for (int s = 0; s < 2; ++s) {  // B tile 256x32: 1024 slots, 2 per thread
      int slot = t + s * 512;
      int row = slot >> 2, ks = slot & 3;
      bf16x8 v = *(const bf16x8*)(WT + (size_t)row * K + k0 + ks * 8);
      int wks = ks ^ ((row >> 1) & 3);
      *(bf16x8*)&Blds[row * 32 + wks * 8] = v;
    }
    __syncthreads();

    bf16x8 fa[4], fb[4];
#pragma unroll
    for (int mr = 0; mr < 4; ++mr) {
      int row = wr * 64 + mr * 16 + lr;
      int ks = lk ^ ((row >> 1) & 3);
      fa[mr] = *(const bf16x8*)&Alds[row * 32 + ks * 8];
    }
#pragma unroll
    for (int nt = 0; nt < 4; ++nt) {
      int r = wc * 64 + nt * 16 + lr;
      int ks = lk ^ ((r >> 1) & 3);
      fb[nt] = *(const bf16x8*)&Blds[r * 32 + ks * 8];
    }
#pragma unroll
    for (int mr = 0; mr < 4; ++mr)
#pragma unroll
      for (int nt = 0; nt < 4; ++nt)
        acc[mr][nt] = __builtin_amdgcn_mfma_f32_16x16x32_bf16(fa[mr], fb[nt], acc[mr][nt], 0, 0, 0);
    __syncthreads();
  }

  const float pa = pa_ptr[0];
#pragma unroll
  for (int mr = 0; mr < 4; ++mr) {
#pragma unroll
    for (int nt = 0; nt < 4; ++nt) {
#pragma unroll
      for (int i = 0; i < 4; ++i) {
        int row = m0 + wr * 64 + mr * 16 + lk * 4 + i;
        int col = wc * 64 + nt * 16 + lr;
        if (row < M) {
          float v = acc[mr][nt][i] + bias[col];
          if constexpr (RESID) v += bf2f(A[(size_t)row * K + col]);
          v = (v >= 0.f) ? v : pa * v;
          outb[(size_t)row * 256 + col] = f2bf(v);
        }
      }
    }
  }
}

// layer-4 GEMM: K=256 -> N=64, no resid, no prelu
__global__ __launch_bounds__(256) void k_gemm_c(const u16* __restrict__ A, const u16* __restrict__ WT,
                                                const float* __restrict__ bias, u16* __restrict__ outb, int M) {
  __shared__ alignas(16) u16 Alds[128 * 32];
  __shared__ alignas(16) u16 Blds[64 * 32];
  const int t = threadIdx.x;
  const int w = t >> 6, l = t & 63;
  const int lr = l & 15, lk = l >> 4;
  const int m0 = blockIdx.x * 128;
  const int K = 256;

  f32x4 acc[2][4];
#pragma unroll
  for (int a = 0; a < 2; ++a)
#pragma unroll
    for (int b = 0; b < 4; ++b)
#pragma unroll
      for (int i = 0; i < 4; ++i) acc[a][b][i] = 0.f;

  for (int k0 = 0; k0 < K; k0 += 32) {
#pragma unroll
    for (int s = 0; s < 2; ++s) {
      int slot = t + s * 256;
      int row = slot >> 2, ks = slot & 3;
      int gm = m0 + row; if (gm >= M) gm = M - 1;
      bf16x8 v = *(const bf16x8*)(A + (size_t)gm * K + k0 + ks * 8);
      int wks = ks ^ ((row >> 1) & 3);
      *(bf16x8*)&Alds[row * 32 + wks * 8] = v;
    }
    {
      int row = t >> 2, ks = t & 3;
      bf16x8 v = *(const bf16x8*)(WT + (size_t)row * K + k0 + ks * 8);
      int wks = ks ^ ((row >> 1) & 3);
      *(bf16x8*)&Blds[row * 32 + wks * 8] = v;
    }
    __syncthreads();

    bf16x8 fa[2], fb[4];
#pragma unroll
    for (int mr = 0; mr < 2; ++mr) {
      int row = w * 32 + mr * 16 + lr;
      int ks = lk ^ ((row >> 1) & 3);
      fa[mr] = *(const bf16x8*)&Alds[row * 32 + ks * 8];
    }
#pragma unroll
    for (int nt = 0; nt < 4; ++nt) {
      int r = nt * 16 + lr;
      int ks = lk ^ ((r >> 1) & 3);
      fb[nt] = *(const bf16x8*)&Blds[r * 32 + ks * 8];
    }
#pragma unroll
    for (int mr = 0; mr < 2; ++mr)
#pragma unroll
      for (int nt = 0; nt < 4; ++nt)
        acc[mr][nt] = __builtin_amdgcn_mfma_f32_16x16x32_bf16(fa[mr], fb[nt], acc[mr][nt], 0, 0, 0);
    __syncthreads();
  }

#pragma unroll
  for (int mr = 0; mr < 2; ++mr) {
#pragma unroll
    for (int nt = 0; nt < 4; ++nt) {
#pragma unroll
      for (int i = 0; i < 4; ++i) {
        int row = m0 + w * 32 + mr * 16 + lk * 4 + i;
        int col = nt * 16 + lr;
        if (row < M) {
          float v = acc[mr][nt][i] + bias[col];
          outb[(size_t)row * CDIM + col] = f2bf(v);
        }
      }
    }
  }
}

// ---------------- CSR build ----------------
__global__ void k_hist(const int* __restrict__ dst, int* __restrict__ cnt, u16* __restrict__ rank, int E) {
  int e = blockIdx.x * blockDim.x + threadIdx.x;
  if (e < E) rank[e] = (u16)atomicAdd(&cnt[dst[e]], 1);
}

__global__ void k_scan1(const int* __restrict__ cnt, int* __restrict__ scn, int* __restrict__ bsum, int n) {
  __shared__ int s[256];
  int i = blockIdx.x * 256 + threadIdx.x;
  int v = (i < n) ? cnt[i] : 0;
  s[threadIdx.x] = v;
  __syncthreads();
  for (int off = 1; off < 256; off <<= 1) {
    int tv = (threadIdx.x >= off) ? s[threadIdx.x - off] : 0;
    __syncthreads();
    s[threadIdx.x] += tv;
    __syncthreads();
  }
  if (i < n) scn[i] = s[threadIdx.x];
  if (threadIdx.x == 255) bsum[blockIdx.x] = s[255];
}

__global__ void k_scan2(int* __restrict__ bsum, int B) {
  __shared__ int s[512];
  int v = (threadIdx.x < B) ? bsum[threadIdx.x] : 0;
  s[threadIdx.x] = v;
  __syncthreads();
  for (int off = 1; off < 512; off <<= 1) {
    int tv = (threadIdx.x >= off) ? s[threadIdx.x - off] : 0;
    __syncthreads();
    s[threadIdx.x] += tv;
    __syncthreads();
  }
  if (threadIdx.x < B) bsum[threadIdx.x] = s[threadIdx.x];
}

__global__ void k_scan3(const int* __restrict__ scn, const int* __restrict__ bsum, int* __restrict__ row_ptr, int n) {
  int i = blockIdx.x * 256 + threadIdx.x;
  if (i < n) {
    int off = (blockIdx.x > 0) ? bsum[blockIdx.x - 1] : 0;
    row_ptr[i + 1] = scn[i] + off;
  }
  if (i == 0) row_ptr[0] = 0;
}

__global__ void k_scatter(const int* __restrict__ src, const int* __restrict__ dst, const float* __restrict__ nrm,
                          const int* __restrict__ row_ptr, const u16* __restrict__ rank,
                          int2* __restrict__ ed, int E) {
  int e = blockIdx.x * blockDim.x + threadIdx.x;
  if (e >= E) return;
  int d = dst[e];
  int pos = row_ptr[d] + (int)rank[e];
  ed[pos] = make_int2(src[e], __builtin_bit_cast(int, nrm[e]));
}

// ---------------- propagation ----------------
__device__ __forceinline__ float wave_sum(float d) {
#pragma unroll
  for (int off = 32; off > 0; off >>= 1) d += __shfl_xor(d, off);
  return d;
}

// pure hop: hn = A_norm @ hc (bf16 state, wave per node, lane = channel)
__global__ void k_hop2(const u16* __restrict__ hc, const int* __restrict__ row_ptr,
                       const int2* __restrict__ ed, u16* __restrict__ hn, int N) {
  int n = blockIdx.x * 4 + (threadIdx.x >> 6);
  int c = threadIdx.x & 63;
  if (n >= N) return;
  int beg = row_ptr[n], end = row_ptr[n + 1];
  int deg = end - beg;

  int2 e0 = make_int2(0, 0);
  if (c < deg) e0 = ed[beg + c];

  float a = 0.f;
  int jn = (deg < 64) ? deg : 64;
  int j = 0;
  for (; j + 7 < jn; j += 8) {
    int s0 = __shfl(e0.x, j + 0), s1 = __shfl(e0.x, j + 1);
    int s2 = __shfl(e0.x, j + 2), s3 = __shfl(e0.x, j + 3);
    int s4 = __shfl(e0.x, j + 4), s5 = __shfl(e0.x, j + 5);
    int s6 = __shfl(e0.x, j + 6), s7 = __shfl(e0.x, j + 7);
    float w0 = __builtin_bit_cast(float, __shfl(e0.y, j + 0));
    float w1 = __builtin_bit_cast(float, __shfl(e0.y, j + 1));
    float w2 = __builtin_bit_cast(float, __shfl(e0.y, j + 2));
    float w3 = __builtin_bit_cast(float, __shfl(e0.y, j + 3));
    float w4 = __builtin_bit_cast(float, __shfl(e0.y, j + 4));
    float w5 = __builtin_bit_cast(float, __shfl(e0.y, j + 5));
    float w6 = __builtin_bit_cast(float, __shfl(e0.y, j + 6));
    float w7 = __builtin_bit_cast(float, __shfl(e0.y, j + 7));
    float h0 = bf2f(hc[(size_t)s0 * CDIM + c]);
    float h1 = bf2f(hc[(size_t)s1 * CDIM + c]);
    float h2 = bf2f(hc[(size_t)s2 * CDIM + c]);
    float h3 = bf2f(hc[(size_t)s3 * CDIM + c]);
    float h4 = bf2f(hc[(size_t)s4 * CDIM + c]);
    float h5 = bf2f(hc[(size_t)s5 * CDIM + c]);
    float h6 = bf2f(hc[(size_t)s6 * CDIM + c]);
    float h7 = bf2f(hc[(size_t)s7 * CDIM + c]);
    a += w0 * h0; a += w1 * h1; a += w2 * h2; a += w3 * h3;
    a += w4 * h4; a += w5 * h5; a += w6 * h6; a += w7 * h7;
  }
  for (; j < jn; ++j) {
    int s = __shfl(e0.x, j);
    float w = __builtin_bit_cast(float, __shfl(e0.y, j));
    a += w * bf2f(hc[(size_t)s * CDIM + c]);
  }
  for (int i = beg + 64; i < end; ++i) {
    int2 e = ed[i];
    a += __builtin_bit_cast(float, e.y) * bf2f(hc[(size_t)e.x * CDIM + c]);
  }
  hn[(size_t)n * CDIM + c] = f2bf(a);
}

// final: scores over all K+1 hops + weighted sum + log-softmax, all in-register
__global__ void k_final(const u16* __restrict__ H, const float* __restrict__ pw, const float* __restrict__ pb,
                        float* __restrict__ out, int N) {
  int n = blockIdx.x * 4 + (threadIdx.x >> 6);
  int c = threadIdx.x & 63;
  if (n >= N) return;
  float pwc = pw[c], pbv = pb[0];
  float acc = 0.f;
  size_t stride = (size_t)N * CDIM;
#pragma unroll
  for (int k = 0; k <= NHOPS; ++k) {
    float v = bf2f(H[(size_t)k * stride + (size_t)n * CDIM + c]);
    float d = wave_sum(v * pwc);
    float sc = 1.f / (1.f + expf(-(d + pbv)));
    acc += sc * v;
  }
  float m = acc;
#pragma unroll
  for (int off = 32; off > 0; off >>= 1) m = fmaxf(m, __shfl_xor(m, off));
  float e = expf(acc - m);
  float s = wave_sum(e);
  out[(size_t)n * CDIM + c] = (acc - m) - logf(s);
}

// ---------------- fallback (small ws) : fused-score path ----------------
__global__ void k_init(const u16* __restrict__ zb, const float* __restrict__ pw, const float* __restrict__ pb,
                       float* __restrict__ oacc, int N) {
  int n = blockIdx.x * 4 + (threadIdx.x >> 6);
  int c = threadIdx.x & 63;
  if (n >= N) return;
  float v = bf2f(zb[(size_t)n * CDIM + c]);
  float d = wave_sum(v * pw[c]);
  float sc = 1.f / (1.f + expf(-(d + pb[0])));
  oacc[(size_t)n * CDIM + c] = sc * v;
}

__global__ void k_hopO(const u16* __restrict__ hc, const int* __restrict__ row_ptr,
                       const int2* __restrict__ ed,
                       const float* __restrict__ pw, const float* __restrict__ pb,
                       u16* __restrict__ hn, float* __restrict__ oacc, int N) {
  int n = blockIdx.x * 4 + (threadIdx.x >> 6);
  int c = threadIdx.x & 63;
  if (n >= N) return;
  int beg = row_ptr[n], end = row_ptr[n + 1];
  int deg = end - beg;
  int2 e0 = make_int2(0, 0);
  if (c < deg) e0 = ed[beg + c];
  float a = 0.f;
  int jn = (deg < 64) ? deg : 64;
  int j = 0;
  for (; j + 3 < jn; j += 4) {
    int s0 = __shfl(e0.x, j), s1 = __shfl(e0.x, j + 1);
    int s2 = __shfl(e0.x, j + 2), s3 = __shfl(e0.x, j + 3);
    float w0 = __builtin_bit_cast(float, __shfl(e0.y, j));
    float w1 = __builtin_bit_cast(float, __shfl(e0.y, j + 1));
    float w2 = __builtin_bit_cast(float, __shfl(e0.y, j + 2));
    float w3 = __builtin_bit_cast(float, __shfl(e0.y, j + 3));
    a += w0 * bf2f(hc[(size_t)s0 * CDIM + c]);
    a += w1 * bf2f(hc[(size_t)s1 * CDIM + c]);
    a += w2 * bf2f(hc[(size_t)s2 * CDIM + c]);
    a += w3 * bf2f(hc[(size_t)s3 * CDIM + c]);
  }
  for (; j < jn; ++j) {
    int s = __shfl(e0.x, j);
    float w = __builtin_bit_cast(float, __shfl(e0.y, j));
    a += w * bf2f(hc[(size_t)s * CDIM + c]);
  }
  for (int i = beg + 64; i < end; ++i) {
    int2 e = ed[i];
    a += __builtin_bit_cast(float, e.y) * bf2f(hc[(size_t)e.x * CDIM + c]);
  }
  hn[(size_t)n * CDIM + c] = f2bf(a);
  float d = wave_sum(a * pw[c]);
  float sc = 1.f / (1.f + expf(-(d + pb[0])));
  oacc[(size_t)n * CDIM + c] += sc * a;
}

__global__ void k_lsm(const float* __restrict__ oacc, float* __restrict__ out, int N) {
  int n = blockIdx.x * 4 + (threadIdx.x >> 6);
  int c = threadIdx.x & 63;
  if (n >= N) return;
  float v = oacc[(size_t)n * CDIM + c];
  float m = v;
#pragma unroll
  for (int off = 32; off > 0; off >>= 1) m = fmaxf(m, __shfl_xor(m, off));
  float e = expf(v - m);
  float s = wave_sum(e);
  out[(size_t)n * CDIM + c] = (v - m) - logf(s);
}

// ---------------- launch ----------------
extern "C" void kernel_launch(void* const* d_in, const int* in_sizes, int n_in,
                              void* d_out, int out_size, void* d_ws, size_t ws_size,
                              hipStream_t stream) {
  const float* x   = (const float*)d_in[0];
  const int*   ei  = (const int*)d_in[1];
  const float* nrm = (const float*)d_in[2];
  const float* W1  = (const float*)d_in[3];
  const float* b1  = (const float*)d_in[4];
  const float* W2  = (const float*)d_in[5];
  const float* b2  = (const float*)d_in[6];
  const float* W3  = (const float*)d_in[7];
  const float* b3  = (const float*)d_in[8];
  const float* W4  = (const float*)d_in[9];
  const float* b4  = (const float*)d_in[10];
  const float* pa  = (const float*)d_in[11];
  const float* pw  = (const float*)d_in[12];
  const float* pb  = (const float*)d_in[13];
  float* out = (float*)d_out;

  const int M = in_sizes[0] / FEATDIM;
  const int E = in_sizes[1] / 2;
  const int* srcI = ei;
  const int* dstI = ei + E;

  char* ws = (char*)d_ws;
  size_t o = 0;
  auto alloc = [&](size_t bytes) { size_t r = o; o += (bytes + 255) & ~(size_t)255; return r; };
  size_t oXB = alloc((size_t)M * FEATDIM * 2);        // xb
  size_t oHA = alloc((size_t)M * HIDDIM * 2);         // hA
  size_t oHB = alloc((size_t)M * HIDDIM * 2);         // hB
  size_t oW1 = alloc((size_t)FEATDIM * HIDDIM * 2);
  size_t oW2 = alloc((size_t)HIDDIM * HIDDIM * 2);
  size_t oW3 = alloc((size_t)HIDDIM * HIDDIM * 2);
  size_t oW4 = alloc((size_t)HIDDIM * CDIM * 2);
  size_t oRP = alloc((size_t)(M + 1) * 4);
  size_t oSC = alloc((size_t)M * 4);
  size_t oBS = alloc(4096);
  size_t oCN = alloc((size_t)M * 4);
  size_t oRK = alloc((size_t)E * 2);                  // u16 rank
  size_t oED = alloc((size_t)E * 8);                  // edge {src, w}
  size_t oH  = alloc((size_t)(NHOPS + 1) * M * CDIM * 2);  // deferred-score H buffers
  bool full = (o <= ws_size);
  // fallback layout pieces live inside oH's budget region if full==false:
  // zb=H0, P0=H1, P1=H2, oacc after (f32)
  size_t oOA = oH + 3 * (((size_t)M * CDIM * 2 + 255) & ~(size_t)255);

  u16*  xb   = (u16*)(ws + oXB);
  u16*  hA   = (u16*)(ws + oHA);
  u16*  hB   = (u16*)(ws + oHB);
  u16*  wt1  = (u16*)(ws + oW1);
  u16*  wt2  = (u16*)(ws + oW2);
  u16*  wt3  = (u16*)(ws + oW3);
  u16*  wt4  = (u16*)(ws + oW4);
  int*  rowp = (int*)(ws + oRP);
  int*  scn  = (int*)(ws + oSC);
  int*  bsum = (int*)(ws + oBS);
  int*  cnt  = (int*)(ws + oCN);
  u16*  rank = (u16*)(ws + oRK);
  int2* ed   = (int2*)(ws + oED);
  u16*  H    = (u16*)(ws + oH);

  // conversions
  k_cvt_x<<<(M * FEATDIM / 8 + 255) / 256, 256, 0, stream>>>(x, xb, M * FEATDIM);
  k_cvt_wt<<<(FEATDIM * HIDDIM + 255) / 256, 256, 0, stream>>>(W1, wt1, FEATDIM, HIDDIM);
  k_cvt_wt<<<(HIDDIM * HIDDIM + 255) / 256, 256, 0, stream>>>(W2, wt2, HIDDIM, HIDDIM);
  k_cvt_wt<<<(HIDDIM * HIDDIM + 255) / 256, 256, 0, stream>>>(W3, wt3, HIDDIM, HIDDIM);
  k_cvt_wt<<<(HIDDIM * CDIM + 255) / 256, 256, 0, stream>>>(W4, wt4, HIDDIM, CDIM);

  // CSR build
  hipMemsetAsync(ws + oCN, 0, (size_t)M * 4, stream);
  k_hist<<<(E + 255) / 256, 256, 0, stream>>>(dstI, cnt, rank, E);
  int nb = (M + 255) / 256;
  k_scan1<<<nb, 256, 0, stream>>>(cnt, scn, bsum, M);
  k_scan2<<<1, 512, 0, stream>>>(bsum, nb);
  k_scan3<<<nb, 256, 0, stream>>>(scn, bsum, rowp, M);
  k_scatter<<<(E + 255) / 256, 256, 0, stream>>>(srcI, dstI, nrm, rowp, rank, ed, E);

  // MLP: BN=256 single-pass-over-A GEMMs for layers 1-3, small GEMM for layer 4
  int gB = (M + 127) / 128;
  u16* zb = H;  // H[0]
  k_gemm_bn<FEATDIM, false><<<gB, 512, 0, stream>>>(xb, wt1, b1, pa, hA, M);
  k_gemm_bn<HIDDIM,  true ><<<gB, 512, 0, stream>>>(hA, wt2, b2, pa, hB, M);
  k_gemm_bn<HIDDIM,  true ><<<gB, 512, 0, stream>>>(hB, wt3, b3, pa, hA, M);
  k_gemm_c<<<gB, 256, 0, stream>>>(hA, wt4, b4, zb, M);

  int nblk = (M + 3) / 4;
  size_t hs = (size_t)M * CDIM;
  if (full) {
    // deferred scoring: hops write H[k+1]; one final pass does scores + lsm
    for (int k = 0; k < NHOPS; ++k)
      k_hop2<<<nblk, 256, 0, stream>>>(H + (size_t)k * hs, rowp, ed, H + (size_t)(k + 1) * hs, M);
    k_final<<<nblk, 256, 0, stream>>>(H, pw, pb, out, M);
  } else {
    u16* P0 = (u16*)(ws + oH + (((size_t)M * CDIM * 2 + 255) & ~(size_t)255));
    u16* P1 = (u16*)(ws + oH + 2 * (((size_t)M * CDIM * 2 + 255) & ~(size_t)255));
    float* oacc = (float*)(ws + oOA);
    k_init<<<nblk, 256, 0, stream>>>(zb, pw, pb, oacc, M);
    const u16* cur = zb;
    for (int k = 0; k < NHOPS; ++k) {
      u16* dbuf = (k & 1) ? P1 : P0;
      k_hopO<<<nblk, 256, 0, stream>>>(cur, rowp, ed, pw, pb, dbuf, oacc, M);
      cur = dbuf;
    }
    k_lsm<<<nblk, 256, 0, stream>>>(oacc, out, M);
  }
}

// Round 5
// 890.755 us; speedup vs baseline: 1.7297x; 1.1252x over previous
//
#include <hip/hip_runtime.h>
#include <stdint.h>
#include <stddef.h>

#define FEATDIM 128
#define HIDDIM  256
#define CDIM    64
#define NHOPS   10

typedef __attribute__((ext_vector_type(8))) short bf16x8;
typedef __attribute__((ext_vector_type(4))) float f32x4;
typedef unsigned short u16;

__device__ __forceinline__ u16 f2bf(float f) {
  uint32_t u = __builtin_bit_cast(uint32_t, f);
  u = (u + 0x7fffu + ((u >> 16) & 1u)) >> 16;
  return (u16)u;
}
__device__ __forceinline__ float bf2f(u16 h) {
  uint32_t u = ((uint32_t)h) << 16;
  return __builtin_bit_cast(float, u);
}

// ---------------- fused weight conversion (all 4 layers, transposed) ----------------
// w f32 [K][N] -> wt bf16 [N][K]
__device__ __forceinline__ void cvt_one(const float* w, u16* wt, int K, int N, int e) {
  int k = e / N, n = e - k * N;
  wt[(size_t)n * K + k] = f2bf(w[e]);
}
__global__ void k_cvt_w(const float* __restrict__ W1, const float* __restrict__ W2,
                        const float* __restrict__ W3, const float* __restrict__ W4,
                        u16* __restrict__ wt1, u16* __restrict__ wt2,
                        u16* __restrict__ wt3, u16* __restrict__ wt4) {
  const int S1 = FEATDIM * HIDDIM;          // 32768
  const int S2 = S1 + HIDDIM * HIDDIM;      // +65536
  const int S3 = S2 + HIDDIM * HIDDIM;
  const int S4 = S3 + HIDDIM * CDIM;
  int e = blockIdx.x * blockDim.x + threadIdx.x;
  if (e < S1)      cvt_one(W1, wt1, FEATDIM, HIDDIM, e);
  else if (e < S2) cvt_one(W2, wt2, HIDDIM, HIDDIM, e - S1);
  else if (e < S3) cvt_one(W3, wt3, HIDDIM, HIDDIM, e - S2);
  else if (e < S4) cvt_one(W4, wt4, HIDDIM, CDIM,  e - S3);
}

// ---------------- bf16 MFMA GEMM, BN = 256 (full hidden), 8 waves ----------------
// A: bf16 [M][K] (or f32 if CVT); WT: bf16 [256][K]; out: bf16 [M][256]; PReLU on.
template<int K, bool RESID, bool CVT>
__global__ __launch_bounds__(512) void k_gemm_bn(const void* __restrict__ Av, const u16* __restrict__ WT,
                                                 const float* __restrict__ bias, const float* __restrict__ pa_ptr,
                                                 u16* __restrict__ outb, int M) {
  __shared__ alignas(16) u16 Alds[128 * 32];
  __shared__ alignas(16) u16 Blds[256 * 32];
  const int t = threadIdx.x;
  const int w = t >> 6, l = t & 63;
  const int wr = w >> 2, wc = w & 3;        // 2x4 wave grid: 64x64 per wave
  const int lr = l & 15, lk = l >> 4;
  const int m0 = blockIdx.x * 128;
  const u16* A = (const u16*)Av;
  const float* Af = (const float*)Av;

  f32x4 acc[4][4];
#pragma unroll
  for (int a = 0; a < 4; ++a)
#pragma unroll
    for (int b = 0; b < 4; ++b)
#pragma unroll
      for (int i = 0; i < 4; ++i) acc[a][b][i] = 0.f;

  for (int k0 = 0; k0 < K; k0 += 32) {
    {  // A tile 128x32: 512 slots, 1 per thread (8 elems)
      int row = t >> 2, ks = t & 3;
      int gm = m0 + row; if (gm >= M) gm = M - 1;
      bf16x8 v;
      if constexpr (CVT) {
        const float4* p = (const float4*)(Af + (size_t)gm * K + k0 + ks * 8);
        float4 a0 = p[0], a1 = p[1];
        v[0] = (short)f2bf(a0.x); v[1] = (short)f2bf(a0.y);
        v[2] = (short)f2bf(a0.z); v[3] = (short)f2bf(a0.w);
        v[4] = (short)f2bf(a1.x); v[5] = (short)f2bf(a1.y);
        v[6] = (short)f2bf(a1.z); v[7] = (short)f2bf(a1.w);
      } else {
        v = *(const bf16x8*)(A + (size_t)gm * K + k0 + ks * 8);
      }
      int wks = ks ^ ((row >> 1) & 3);
      *(bf16x8*)&Alds[row * 32 + wks * 8] = v;
    }
#pragma unroll
    for (int s = 0; s < 2; ++s) {  // B tile 256x32: 1024 slots, 2 per thread
      int slot = t + s * 512;
      int row = slot >> 2, ks = slot & 3;
      bf16x8 v = *(const bf16x8*)(WT + (size_t)row * K + k0 + ks * 8);
      int wks = ks ^ ((row >> 1) & 3);
      *(bf16x8*)&Blds[row * 32 + wks * 8] = v;
    }
    __syncthreads();

    bf16x8 fa[4], fb[4];
#pragma unroll
    for (int mr = 0; mr < 4; ++mr) {
      int row = wr * 64 + mr * 16 + lr;
      int ks = lk ^ ((row >> 1) & 3);
      fa[mr] = *(const bf16x8*)&Alds[row * 32 + ks * 8];
    }
#pragma unroll
    for (int nt = 0; nt < 4; ++nt) {
      int r = wc * 64 + nt * 16 + lr;
      int ks = lk ^ ((r >> 1) & 3);
      fb[nt] = *(const bf16x8*)&Blds[r * 32 + ks * 8];
    }
#pragma unroll
    for (int mr = 0; mr < 4; ++mr)
#pragma unroll
      for (int nt = 0; nt < 4; ++nt)
        acc[mr][nt] = __builtin_amdgcn_mfma_f32_16x16x32_bf16(fa[mr], fb[nt], acc[mr][nt], 0, 0, 0);
    __syncthreads();
  }

  const float pa = pa_ptr[0];
#pragma unroll
  for (int mr = 0; mr < 4; ++mr) {
#pragma unroll
    for (int nt = 0; nt < 4; ++nt) {
#pragma unroll
      for (int i = 0; i < 4; ++i) {
        int row = m0 + wr * 64 + mr * 16 + lk * 4 + i;
        int col = wc * 64 + nt * 16 + lr;
        if (row < M) {
          float v = acc[mr][nt][i] + bias[col];
          if constexpr (RESID) v += bf2f(A[(size_t)row * K + col]);
          v = (v >= 0.f) ? v : pa * v;
          outb[(size_t)row * 256 + col] = f2bf(v);
        }
      }
    }
  }
}

// layer-4 GEMM: K=256 -> N=64
__global__ __launch_bounds__(256) void k_gemm_c(const u16* __restrict__ A, const u16* __restrict__ WT,
                                                const float* __restrict__ bias, u16* __restrict__ outb, int M) {
  __shared__ alignas(16) u16 Alds[128 * 32];
  __shared__ alignas(16) u16 Blds[64 * 32];
  const int t = threadIdx.x;
  const int w = t >> 6, l = t & 63;
  const int lr = l & 15, lk = l >> 4;
  const int m0 = blockIdx.x * 128;
  const int K = 256;

  f32x4 acc[2][4];
#pragma unroll
  for (int a = 0; a < 2; ++a)
#pragma unroll
    for (int b = 0; b < 4; ++b)
#pragma unroll
      for (int i = 0; i < 4; ++i) acc[a][b][i] = 0.f;

  for (int k0 = 0; k0 < K; k0 += 32) {
#pragma unroll
    for (int s = 0; s < 2; ++s) {
      int slot = t + s * 256;
      int row = slot >> 2, ks = slot & 3;
      int gm = m0 + row; if (gm >= M) gm = M - 1;
      bf16x8 v = *(const bf16x8*)(A + (size_t)gm * K + k0 + ks * 8);
      int wks = ks ^ ((row >> 1) & 3);
      *(bf16x8*)&Alds[row * 32 + wks * 8] = v;
    }
    {
      int row = t >> 2, ks = t & 3;
      bf16x8 v = *(const bf16x8*)(WT + (size_t)row * K + k0 + ks * 8);
      int wks = ks ^ ((row >> 1) & 3);
      *(bf16x8*)&Blds[row * 32 + wks * 8] = v;
    }
    __syncthreads();

    bf16x8 fa[2], fb[4];
#pragma unroll
    for (int mr = 0; mr < 2; ++mr) {
      int row = w * 32 + mr * 16 + lr;
      int ks = lk ^ ((row >> 1) & 3);
      fa[mr] = *(const bf16x8*)&Alds[row * 32 + ks * 8];
    }
#pragma unroll
    for (int nt = 0; nt < 4; ++nt) {
      int r = nt * 16 + lr;
      int ks = lk ^ ((r >> 1) & 3);
      fb[nt] = *(const bf16x8*)&Blds[r * 32 + ks * 8];
    }
#pragma unroll
    for (int mr = 0; mr < 2; ++mr)
#pragma unroll
      for (int nt = 0; nt < 4; ++nt)
        acc[mr][nt] = __builtin_amdgcn_mfma_f32_16x16x32_bf16(fa[mr], fb[nt], acc[mr][nt], 0, 0, 0);
    __syncthreads();
  }

#pragma unroll
  for (int mr = 0; mr < 2; ++mr) {
#pragma unroll
    for (int nt = 0; nt < 4; ++nt) {
#pragma unroll
      for (int i = 0; i < 4; ++i) {
        int row = m0 + w * 32 + mr * 16 + lk * 4 + i;
        int col = nt * 16 + lr;
        if (row < M) {
          float v = acc[mr][nt][i] + bias[col];
          outb[(size_t)row * CDIM + col] = f2bf(v);
        }
      }
    }
  }
}

// ---------------- CSR build ----------------
__global__ void k_hist(const int* __restrict__ dst, int* __restrict__ cnt, u16* __restrict__ rank, int E) {
  int e = blockIdx.x * blockDim.x + threadIdx.x;
  if (e < E) rank[e] = (u16)atomicAdd(&cnt[dst[e]], 1);
}

__global__ void k_scan1(const int* __restrict__ cnt, int* __restrict__ scn, int* __restrict__ bsum, int n) {
  __shared__ int s[256];
  int i = blockIdx.x * 256 + threadIdx.x;
  int v = (i < n) ? cnt[i] : 0;
  s[threadIdx.x] = v;
  __syncthreads();
  for (int off = 1; off < 256; off <<= 1) {
    int tv = (threadIdx.x >= off) ? s[threadIdx.x - off] : 0;
    __syncthreads();
    s[threadIdx.x] += tv;
    __syncthreads();
  }
  if (i < n) scn[i] = s[threadIdx.x];
  if (threadIdx.x == 255) bsum[blockIdx.x] = s[255];
}

__global__ void k_scan2(int* __restrict__ bsum, int B) {
  __shared__ int s[512];
  int v = (threadIdx.x < B) ? bsum[threadIdx.x] : 0;
  s[threadIdx.x] = v;
  __syncthreads();
  for (int off = 1; off < 512; off <<= 1) {
    int tv = (threadIdx.x >= off) ? s[threadIdx.x - off] : 0;
    __syncthreads();
    s[threadIdx.x] += tv;
    __syncthreads();
  }
  if (threadIdx.x < B) bsum[threadIdx.x] = s[threadIdx.x];
}

__global__ void k_scan3(const int* __restrict__ scn, const int* __restrict__ bsum, int* __restrict__ row_ptr, int n) {
  int i = blockIdx.x * 256 + threadIdx.x;
  if (i < n) {
    int off = (blockIdx.x > 0) ? bsum[blockIdx.x - 1] : 0;
    row_ptr[i + 1] = scn[i] + off;
  }
  if (i == 0) row_ptr[0] = 0;
}

__global__ void k_scatter(const int* __restrict__ src, const int* __restrict__ dst, const float* __restrict__ nrm,
                          const int* __restrict__ row_ptr, const u16* __restrict__ rank,
                          int2* __restrict__ ed, int E) {
  int e = blockIdx.x * blockDim.x + threadIdx.x;
  if (e >= E) return;
  int d = dst[e];
  int pos = row_ptr[d] + (int)rank[e];
  ed[pos] = make_int2(src[e], __builtin_bit_cast(int, nrm[e]));
}

// ---------------- propagation ----------------
__device__ __forceinline__ float wave_sum(float d) {
#pragma unroll
  for (int off = 32; off > 0; off >>= 1) d += __shfl_xor(d, off);
  return d;
}

// paired-edge hop: lane halves process 2 edges/iter; u32 gathers (2 channels/lane)
__global__ void k_hop2(const u16* __restrict__ hc, const int* __restrict__ row_ptr,
                       const int2* __restrict__ ed, u16* __restrict__ hn, int N) {
  int n = blockIdx.x * 4 + (threadIdx.x >> 6);
  int l = threadIdx.x & 63;
  int half = l >> 5;       // which edge of the pair this lane handles
  int cl = l & 31;         // channel-pair index: channels 2cl, 2cl+1
  if (n >= N) return;
  int beg = row_ptr[n], end = row_ptr[n + 1];
  int deg = end - beg;

  // wave-cooperative prefetch: lane l holds edge beg+l
  int2 e0 = make_int2(0, 0);
  if (l < deg) e0 = ed[beg + l];

  const uint32_t* h32 = (const uint32_t*)hc;
  float ax = 0.f, ay = 0.f;
  int jn = (deg < 64) ? deg : 64;
  int jfull = jn & ~7;     // multiple of 8 edges (4 pair-iters)
  int j = 0;
  for (; j < jfull; j += 8) {
    int i0 = j + 0 + half, i1 = j + 2 + half, i2 = j + 4 + half, i3 = j + 6 + half;
    int s0 = __shfl(e0.x, i0), s1 = __shfl(e0.x, i1);
    int s2 = __shfl(e0.x, i2), s3 = __shfl(e0.x, i3);
    float w0 = __builtin_bit_cast(float, __shfl(e0.y, i0));
    float w1 = __builtin_bit_cast(float, __shfl(e0.y, i1));
    float w2 = __builtin_bit_cast(float, __shfl(e0.y, i2));
    float w3 = __builtin_bit_cast(float, __shfl(e0.y, i3));
    uint32_t u0 = h32[(size_t)s0 * 32 + cl];
    uint32_t u1 = h32[(size_t)s1 * 32 + cl];
    uint32_t u2 = h32[(size_t)s2 * 32 + cl];
    uint32_t u3 = h32[(size_t)s3 * 32 + cl];
    ax += w0 * __builtin_bit_cast(float, u0 << 16);
    ay += w0 * __builtin_bit_cast(float, u0 & 0xffff0000u);
    ax += w1 * __builtin_bit_cast(float, u1 << 16);
    ay += w1 * __builtin_bit_cast(float, u1 & 0xffff0000u);
    ax += w2 * __builtin_bit_cast(float, u2 << 16);
    ay += w2 * __builtin_bit_cast(float, u2 & 0xffff0000u);
    ax += w3 * __builtin_bit_cast(float, u3 << 16);
    ay += w3 * __builtin_bit_cast(float, u3 & 0xffff0000u);
  }
  for (; j < jn; j += 2) {
    int idx = j + half;
    bool v = idx < jn;
    int si = v ? idx : 0;
    int s = __shfl(e0.x, si);
    float w = __builtin_bit_cast(float, __shfl(e0.y, si));
    if (!v) w = 0.f;
    uint32_t u = h32[(size_t)s * 32 + cl];
    ax += w * __builtin_bit_cast(float, u << 16);
    ay += w * __builtin_bit_cast(float, u & 0xffff0000u);
  }
  // rare overflow (deg > 64)
  for (int i = beg + 64; i < end; i += 2) {
    int ii = i + half;
    bool v = ii < end;
    int2 e = ed[v ? ii : (end - 1)];
    float w = v ? __builtin_bit_cast(float, e.y) : 0.f;
    uint32_t u = h32[(size_t)e.x * 32 + cl];
    ax += w * __builtin_bit_cast(float, u << 16);
    ay += w * __builtin_bit_cast(float, u & 0xffff0000u);
  }

  // combine the two halves, store from lanes 0-31 (4B each)
  ax += __shfl_xor(ax, 32);
  ay += __shfl_xor(ay, 32);
  if (half == 0) {
    uint32_t o = ((uint32_t)f2bf(ay) << 16) | (uint32_t)f2bf(ax);
    ((uint32_t*)hn)[(size_t)n * 32 + cl] = o;
  }
}

// final: scores over all K+1 hops + weighted sum + log-softmax, in-register
__global__ void k_final(const u16* __restrict__ H, const float* __restrict__ pw, const float* __restrict__ pb,
                        float* __restrict__ out, int N) {
  int n = blockIdx.x * 4 + (threadIdx.x >> 6);
  int c = threadIdx.x & 63;
  if (n >= N) return;
  float pwc = pw[c], pbv = pb[0];
  float acc = 0.f;
  size_t stride = (size_t)N * CDIM;
#pragma unroll
  for (int k = 0; k <= NHOPS; ++k) {
    float v = bf2f(H[(size_t)k * stride + (size_t)n * CDIM + c]);
    float d = wave_sum(v * pwc);
    float sc = 1.f / (1.f + expf(-(d + pbv)));
    acc += sc * v;
  }
  float m = acc;
#pragma unroll
  for (int off = 32; off > 0; off >>= 1) m = fmaxf(m, __shfl_xor(m, off));
  float e = expf(acc - m);
  float s = wave_sum(e);
  out[(size_t)n * CDIM + c] = (acc - m) - logf(s);
}

// ---------------- launch ----------------
extern "C" void kernel_launch(void* const* d_in, const int* in_sizes, int n_in,
                              void* d_out, int out_size, void* d_ws, size_t ws_size,
                              hipStream_t stream) {
  const float* x   = (const float*)d_in[0];
  const int*   ei  = (const int*)d_in[1];
  const float* nrm = (const float*)d_in[2];
  const float* W1  = (const float*)d_in[3];
  const float* b1  = (const float*)d_in[4];
  const float* W2  = (const float*)d_in[5];
  const float* b2  = (const float*)d_in[6];
  const float* W3  = (const float*)d_in[7];
  const float* b3  = (const float*)d_in[8];
  const float* W4  = (const float*)d_in[9];
  const float* b4  = (const float*)d_in[10];
  const float* pa  = (const float*)d_in[11];
  const float* pw  = (const float*)d_in[12];
  const float* pb  = (const float*)d_in[13];
  float* out = (float*)d_out;

  const int M = in_sizes[0] / FEATDIM;
  const int E = in_sizes[1] / 2;
  const int* srcI = ei;
  const int* dstI = ei + E;

  // ---- workspace layout (aliased; total ~155 MB) ----
  // [0]                : H  = [NHOPS+1][M][64] bf16  (140.8 MB)
  //   H[0] = zb (GEMM4 out); hA aliases H[1..4]; hB aliases H[5..8];
  //   cnt/scn/rank alias H[9..] (dead after CSR build, hops write them late)
  // [11*hs]            : wt1..wt4, rowp, bsum, ed
  char* ws = (char*)d_ws;
  const size_t hs = ((size_t)M * CDIM * 2 + 255) & ~(size_t)255;   // one H slice
  size_t o = 11 * hs;
  auto alloc = [&](size_t bytes) { size_t r = o; o += (bytes + 255) & ~(size_t)255; return r; };
  size_t oW1 = alloc((size_t)FEATDIM * HIDDIM * 2);
  size_t oW2 = alloc((size_t)HIDDIM * HIDDIM * 2);
  size_t oW3 = alloc((size_t)HIDDIM * HIDDIM * 2);
  size_t oW4 = alloc((size_t)HIDDIM * CDIM * 2);
  size_t oRP = alloc((size_t)(M + 1) * 4);
  size_t oBS = alloc(4096);
  size_t oED = alloc((size_t)E * 8);

  u16*  H    = (u16*)ws;
  u16*  zb   = H;                              // H[0]
  u16*  hA   = (u16*)(ws + 1 * hs);            // H[1..4]
  u16*  hB   = (u16*)(ws + 5 * hs);            // H[5..8]
  int*  cnt  = (int*)(ws + 9 * hs);            // M*4  (dead before hop8 writes H[9])
  int*  scn  = (int*)(ws + 9 * hs + (((size_t)M * 4 + 255) & ~(size_t)255));
  u16*  rank = (u16*)(ws + 9 * hs + 2 * (((size_t)M * 4 + 255) & ~(size_t)255));  // E*2
  u16*  wt1  = (u16*)(ws + oW1);
  u16*  wt2  = (u16*)(ws + oW2);
  u16*  wt3  = (u16*)(ws + oW3);
  u16*  wt4  = (u16*)(ws + oW4);
  int*  rowp = (int*)(ws + oRP);
  int*  bsum = (int*)(ws + oBS);
  int2* ed   = (int2*)(ws + oED);

  // weight conversions (one kernel)
  {
    const int tot = FEATDIM * HIDDIM + 2 * HIDDIM * HIDDIM + HIDDIM * CDIM;
    k_cvt_w<<<(tot + 255) / 256, 256, 0, stream>>>(W1, W2, W3, W4, wt1, wt2, wt3, wt4);
  }

  // CSR build
  hipMemsetAsync(cnt, 0, (size_t)M * 4, stream);
  k_hist<<<(E + 255) / 256, 256, 0, stream>>>(dstI, cnt, rank, E);
  int nb = (M + 255) / 256;
  k_scan1<<<nb, 256, 0, stream>>>(cnt, scn, bsum, M);
  k_scan2<<<1, 512, 0, stream>>>(bsum, nb);
  k_scan3<<<nb, 256, 0, stream>>>(scn, bsum, rowp, M);
  k_scatter<<<(E + 255) / 256, 256, 0, stream>>>(srcI, dstI, nrm, rowp, rank, ed, E);

  // MLP (layer 1 converts x f32->bf16 in staging)
  int gB = (M + 127) / 128;
  k_gemm_bn<FEATDIM, false, true ><<<gB, 512, 0, stream>>>(x,  wt1, b1, pa, hA, M);
  k_gemm_bn<HIDDIM,  true,  false><<<gB, 512, 0, stream>>>(hA, wt2, b2, pa, hB, M);
  k_gemm_bn<HIDDIM,  true,  false><<<gB, 512, 0, stream>>>(hB, wt3, b3, pa, hA, M);
  k_gemm_c<<<gB, 256, 0, stream>>>(hA, wt4, b4, zb, M);

  // propagation: hops write H[k+1]; one final pass does scores + log-softmax
  int nblk = (M + 3) / 4;
  size_t hsel = (size_t)M * CDIM;
  for (int k = 0; k < NHOPS; ++k)
    k_hop2<<<nblk, 256, 0, stream>>>(H + (size_t)k * hsel, rowp, ed, H + (size_t)(k + 1) * hsel, M);
  k_final<<<nblk, 256, 0, stream>>>(H, pw, pb, out, M);
}